// Round 2
// baseline (1174.569 us; speedup 1.0000x reference)
//
#include <hip/hip_runtime.h>

#define D 128
#define NEGS 0.2f

__device__ __forceinline__ float lrelu(float x){ return x > 0.f ? x : NEGS*x; }

// ---------------- W transpose (tiny, once per launch) ----------------
__global__ __launch_bounds__(256) void k_transpose(const float* __restrict__ Wsrc,
        const float* __restrict__ Wres, float* __restrict__ WTs, float* __restrict__ WTr){
    int t = blockIdx.x*256 + threadIdx.x;  // 0..16383
    if (t < 16384){
        int j = t >> 7, k = t & 127;       // coalesced read over k
        WTs[k*128 + j] = Wsrc[t];
        WTr[k*128 + j] = Wres[t];
    }
}

// ---------------- GEMM: xp = feats@Wsrc^T, res(d_out) = feats@Wres^T ----------------
__global__ __launch_bounds__(256) void k_gemm(const float* __restrict__ feats,
        const float* __restrict__ WTs, const float* __restrict__ WTr,
        float* __restrict__ xp, float* __restrict__ res, int n){
    __shared__ float fs[64][128];
    int t = threadIdx.x;
    int n0 = blockIdx.x * 64;
    const float4* f4 = (const float4*)feats;
    #pragma unroll
    for (int i = 0; i < 8; ++i){
        int idx = t + i*256;               // 2048 float4 units
        int row = idx >> 5, c4 = idx & 31;
        float4 v = make_float4(0.f,0.f,0.f,0.f);
        if (n0 + row < n) v = f4[(size_t)(n0+row)*32 + c4];
        fs[row][c4*4+0]=v.x; fs[row][c4*4+1]=v.y; fs[row][c4*4+2]=v.z; fs[row][c4*4+3]=v.w;
    }
    __syncthreads();
    int tn = t >> 5;          // 8 node groups
    int tc = t & 31;          // 32 col groups
    int j0 = tc*4;
    float acc[8][4], acr[8][4];
    #pragma unroll
    for(int i=0;i<8;++i){
        #pragma unroll
        for(int c=0;c<4;++c){ acc[i][c]=0.f; acr[i][c]=0.f; }
    }
    #pragma unroll 4
    for (int k=0;k<128;++k){
        float4 wv = *(const float4*)(WTs + k*128 + j0);
        float4 rv = *(const float4*)(WTr + k*128 + j0);
        #pragma unroll
        for (int i=0;i<8;++i){
            float f = fs[tn*8+i][k];
            acc[i][0]+=f*wv.x; acc[i][1]+=f*wv.y; acc[i][2]+=f*wv.z; acc[i][3]+=f*wv.w;
            acr[i][0]+=f*rv.x; acr[i][1]+=f*rv.y; acr[i][2]+=f*rv.z; acr[i][3]+=f*rv.w;
        }
    }
    #pragma unroll
    for(int i=0;i<8;++i){
        int nn = n0 + tn*8 + i;
        if (nn < n){
            *(float4*)(xp  + (size_t)nn*128 + j0) = make_float4(acc[i][0],acc[i][1],acc[i][2],acc[i][3]);
            *(float4*)(res + (size_t)nn*128 + j0) = make_float4(acr[i][0],acr[i][1],acr[i][2],acr[i][3]);
        }
    }
}

// ---------------- attention scalar per node: a = sum_c xp[n,h,c]*att[h,c] ----------------
__global__ __launch_bounds__(256) void k_attn(const float* __restrict__ xp,
        const float* __restrict__ att_s, const float* __restrict__ att_d,
        float* __restrict__ a_src, float* __restrict__ a_dst, int n){
    int w = threadIdx.x >> 6, lane = threadIdx.x & 63;
    int node = blockIdx.x*4 + w;
    if (node >= n) return;
    float x0 = xp[(size_t)node*128 + lane];
    float x1 = xp[(size_t)node*128 + 64 + lane];
    float s0 = x0 * att_s[lane],    s1 = x1 * att_s[64+lane];
    float d0 = x0 * att_d[lane],    d1 = x1 * att_d[64+lane];
    #pragma unroll
    for (int off=16; off; off>>=1){
        s0 += __shfl_xor(s0, off); s1 += __shfl_xor(s1, off);
        d0 += __shfl_xor(d0, off); d1 += __shfl_xor(d1, off);
    }
    if ((lane & 31) == 0){
        int h = lane >> 5;  // 0 or 1
        a_src[node*4 + h]     = s0;
        a_src[node*4 + 2 + h] = s1;
        a_dst[node*4 + h]     = d0;
        a_dst[node*4 + 2 + h] = d1;
    }
}

// ---------------- CSR build ----------------
__global__ void k_deg(const int* __restrict__ ei, int* __restrict__ deg, int e){
    int i = blockIdx.x*blockDim.x + threadIdx.x;
    if (i < e) atomicAdd(&deg[ei[e + i]], 1);
}

__global__ __launch_bounds__(256) void k_bsum(const int* __restrict__ deg, int* __restrict__ bsum, int n){
    __shared__ int sm[256];
    int i = blockIdx.x*256 + threadIdx.x;
    sm[threadIdx.x] = (i<n)? deg[i] : 0;
    __syncthreads();
    for (int s=128; s; s>>=1){ if ((int)threadIdx.x < s) sm[threadIdx.x]+=sm[threadIdx.x+s]; __syncthreads(); }
    if (!threadIdx.x) bsum[blockIdx.x] = sm[0];
}

__global__ void k_bscan(const int* __restrict__ bsum, int* __restrict__ boff, int nb){
    if (threadIdx.x==0 && blockIdx.x==0){
        int run=0;
        for (int b=0;b<nb;++b){ boff[b]=run; run+=bsum[b]; }
    }
}

__global__ __launch_bounds__(256) void k_scan(const int* __restrict__ deg, const int* __restrict__ boff,
        int* __restrict__ offs, int n){
    __shared__ int sm[256];
    int i = blockIdx.x*256 + threadIdx.x;
    int v = (i<n)? deg[i]:0;
    sm[threadIdx.x]=v;
    __syncthreads();
    for (int s=1;s<256;s<<=1){
        int add = ((int)threadIdx.x>=s)? sm[threadIdx.x-s]:0;
        __syncthreads();
        sm[threadIdx.x]+=add;
        __syncthreads();
    }
    int excl = sm[threadIdx.x]-v;
    if (i<=n) offs[i]=boff[blockIdx.x]+excl;
}

__global__ void k_scatter(const int* __restrict__ ei, const int* __restrict__ offs,
        int* __restrict__ cursor, int* __restrict__ nbr, int e){
    int i = blockIdx.x*blockDim.x + threadIdx.x;
    if (i<e){
        int s = ei[i], d = ei[e+i];
        int pos = atomicAdd(&cursor[d],1);
        nbr[offs[d]+pos] = s;
    }
}

// ---------------- fused softmax + aggregation + residual + BN partials ----------------
__global__ __launch_bounds__(256) void k_aggr(const float* __restrict__ xp,
        const float* __restrict__ a_src, const float* __restrict__ a_dst,
        const int* __restrict__ offs, const int* __restrict__ nbr,
        const float* __restrict__ bias, float* __restrict__ out,
        float* __restrict__ gsum, float* __restrict__ gsq, int n){
    __shared__ float lsum[4][128];
    __shared__ float lsq[4][128];
    int w = threadIdx.x>>6, lane = threadIdx.x & 63;
    int node = blockIdx.x*4 + w;
    float o0=0.f, o1=0.f;
    if (node < n) {
        const float4 ad  = *(const float4*)(a_dst + node*4);
        const float4 asf = *(const float4*)(a_src + node*4);
        float es0 = lrelu(asf.x+ad.x), es1=lrelu(asf.y+ad.y);
        float es2 = lrelu(asf.z+ad.z), es3=lrelu(asf.w+ad.w);
        int beg = offs[node], end = offs[node+1];
        int deg = end-beg;
        float m0=es0,m1=es1,m2=es2,m3=es3;
        for (int base=0;base<deg;base+=64){
            int i = base+lane;
            if (i<deg){
                int sid = nbr[beg+i];
                const float4 av = *(const float4*)(a_src + sid*4);
                m0 = fmaxf(m0, lrelu(av.x+ad.x));
                m1 = fmaxf(m1, lrelu(av.y+ad.y));
                m2 = fmaxf(m2, lrelu(av.z+ad.z));
                m3 = fmaxf(m3, lrelu(av.w+ad.w));
            }
        }
        #pragma unroll
        for (int off=32;off;off>>=1){
            m0=fmaxf(m0,__shfl_xor(m0,off)); m1=fmaxf(m1,__shfl_xor(m1,off));
            m2=fmaxf(m2,__shfl_xor(m2,off)); m3=fmaxf(m3,__shfl_xor(m3,off));
        }
        float exs0=__expf(es0-m0), exs1=__expf(es1-m1), exs2=__expf(es2-m2), exs3=__expf(es3-m3);
        float sh0=0.f,sh1=0.f,sh2=0.f,sh3=0.f;
        const float* xn = xp + (size_t)node*128;
        float acc0 = ((lane<32)?exs0:exs1) * xn[lane];
        float acc1 = ((lane<32)?exs2:exs3) * xn[64+lane];
        for (int base=0;base<deg;base+=64){
            int i = base+lane;
            int cnt = min(64, deg-base);
            int sid = 0;
            float x0=0.f,x1=0.f,x2=0.f,x3=0.f;
            if (i<deg){
                sid = nbr[beg+i];
                const float4 av = *(const float4*)(a_src + sid*4);
                x0 = __expf(lrelu(av.x+ad.x)-m0);
                x1 = __expf(lrelu(av.y+ad.y)-m1);
                x2 = __expf(lrelu(av.z+ad.z)-m2);
                x3 = __expf(lrelu(av.w+ad.w)-m3);
                sh0+=x0; sh1+=x1; sh2+=x2; sh3+=x3;
            }
            for (int q=0;q<cnt;++q){
                int ss = __shfl(sid,q);
                float q0=__shfl(x0,q), q1=__shfl(x1,q), q2=__shfl(x2,q), q3=__shfl(x3,q);
                const float* xr = xp + (size_t)ss*128;
                acc0 += ((lane<32)?q0:q1) * xr[lane];
                acc1 += ((lane<32)?q2:q3) * xr[64+lane];
            }
        }
        #pragma unroll
        for (int off=32;off;off>>=1){
            sh0+=__shfl_xor(sh0,off); sh1+=__shfl_xor(sh1,off);
            sh2+=__shfl_xor(sh2,off); sh3+=__shfl_xor(sh3,off);
        }
        float s0=sh0+exs0, s1=sh1+exs1, s2=sh2+exs2, s3=sh3+exs3;
        float i0 = 1.f/(((lane<32)?s0:s1)+1e-16f);
        float i1 = 1.f/(((lane<32)?s2:s3)+1e-16f);
        o0 = acc0*i0 + out[(size_t)node*128+lane]    + bias[lane];
        o1 = acc1*i1 + out[(size_t)node*128+64+lane] + bias[64+lane];
        out[(size_t)node*128+lane]    = o0;
        out[(size_t)node*128+64+lane] = o1;
    }
    lsum[w][lane]=o0;      lsum[w][64+lane]=o1;
    lsq[w][lane]=o0*o0;    lsq[w][64+lane]=o1*o1;
    __syncthreads();
    int t = threadIdx.x;
    if (t < 128){
        float s = lsum[0][t]+lsum[1][t]+lsum[2][t]+lsum[3][t];
        atomicAdd(&gsum[t], s);
    } else {
        int c = t-128;
        float s = lsq[0][c]+lsq[1][c]+lsq[2][c]+lsq[3][c];
        atomicAdd(&gsq[c], s);
    }
}

// ---------------- BN finalize + apply ----------------
__global__ void k_bnfin(const float* __restrict__ gsum, const float* __restrict__ gsq,
        const float* __restrict__ gamma, const float* __restrict__ beta,
        float* __restrict__ scale, float* __restrict__ shift, int n){
    int t = threadIdx.x;
    if (t < 128){
        float mu  = gsum[t]/(float)n;
        float var = gsq[t]/(float)n - mu*mu;
        float inv = rsqrtf(var + 1e-5f);
        float sc  = inv*gamma[t];
        scale[t] = sc;
        shift[t] = beta[t] - mu*sc;
    }
}

__global__ __launch_bounds__(256) void k_bnapply(float* __restrict__ out,
        const float* __restrict__ scale, const float* __restrict__ shift, long total4){
    __shared__ float sc[128], sh[128];
    if (threadIdx.x < 128){ sc[threadIdx.x]=scale[threadIdx.x]; sh[threadIdx.x]=shift[threadIdx.x]; }
    __syncthreads();
    long i = (long)blockIdx.x*blockDim.x + threadIdx.x;
    if (i < total4){
        float4* o4 = (float4*)out;
        float4 v = o4[i];
        int c = (int)((i & 31) * 4);
        v.x = v.x*sc[c+0]+sh[c+0];
        v.y = v.y*sc[c+1]+sh[c+1];
        v.z = v.z*sc[c+2]+sh[c+2];
        v.w = v.w*sc[c+3]+sh[c+3];
        o4[i]=v;
    }
}

extern "C" void kernel_launch(void* const* d_in, const int* in_sizes, int n_in,
                              void* d_out, int out_size, void* d_ws, size_t ws_size,
                              hipStream_t stream){
    const float* feats      = (const float*)d_in[0];
    const int* ei           = (const int*)d_in[1];   // harness converts int64 -> int32
    const float* Wsrc       = (const float*)d_in[2];
    const float* att_s      = (const float*)d_in[3];
    const float* att_d      = (const float*)d_in[4];
    const float* Wres       = (const float*)d_in[5];
    const float* bias       = (const float*)d_in[6];
    const float* gamma      = (const float*)d_in[7];
    const float* beta       = (const float*)d_in[8];
    int n = in_sizes[0]/128;
    int e = in_sizes[1]/2;
    float* out = (float*)d_out;

    char* w = (char*)d_ws;
    float* xp    = (float*)w; w += (size_t)n*128*4;
    float* a_src = (float*)w; w += (size_t)n*4*4;
    float* a_dst = (float*)w; w += (size_t)n*4*4;
    int*   deg   = (int*)w;   w += (size_t)n*4;
    int*   cursor= (int*)w;   w += (size_t)n*4;
    int*   offs  = (int*)w;   w += ((size_t)n+8)*4;
    int*   nbr   = (int*)w;   w += (size_t)e*4;
    int nb = (n+255)/256;
    int*   bsum  = (int*)w;   w += ((size_t)nb+8)*4;
    int*   boff  = (int*)w;   w += ((size_t)nb+8)*4;
    float* gsum  = (float*)w; w += 512;
    float* gsq   = (float*)w; w += 512;
    float* scale = (float*)w; w += 512;
    float* shift = (float*)w; w += 512;
    float* WTs   = (float*)w; w += 128*128*4;
    float* WTr   = (float*)w; w += 128*128*4;

    hipMemsetAsync(deg,    0, (size_t)n*4, stream);
    hipMemsetAsync(cursor, 0, (size_t)n*4, stream);
    hipMemsetAsync(gsum,   0, 512, stream);
    hipMemsetAsync(gsq,    0, 512, stream);

    k_transpose<<<dim3(64), 256, 0, stream>>>(Wsrc, Wres, WTs, WTr);
    k_gemm<<<dim3((n+63)/64), 256, 0, stream>>>(feats, WTs, WTr, xp, out, n);
    k_attn<<<dim3((n+3)/4), 256, 0, stream>>>(xp, att_s, att_d, a_src, a_dst, n);
    k_deg<<<dim3((e+255)/256), 256, 0, stream>>>(ei, deg, e);
    k_bsum<<<dim3(nb), 256, 0, stream>>>(deg, bsum, n);
    k_bscan<<<dim3(1), 64, 0, stream>>>(bsum, boff, nb);
    k_scan<<<dim3(nb), 256, 0, stream>>>(deg, boff, offs, n);
    k_scatter<<<dim3((e+255)/256), 256, 0, stream>>>(ei, offs, cursor, nbr, e);
    k_aggr<<<dim3((n+3)/4), 256, 0, stream>>>(xp, a_src, a_dst, offs, nbr, bias, out, gsum, gsq, n);
    k_bnfin<<<dim3(1), 128, 0, stream>>>(gsum, gsq, gamma, beta, scale, shift, n);
    long total4 = (long)n*32;
    k_bnapply<<<dim3((int)((total4+255)/256)), 256, 0, stream>>>(out, scale, shift, total4);
}

// Round 3
// 1171.123 us; speedup vs baseline: 1.0029x; 1.0029x over previous
//
#include <hip/hip_runtime.h>

#define NEGS 0.2f

__device__ __forceinline__ float lrelu(float x){ return x > 0.f ? x : NEGS*x; }
__device__ __forceinline__ float sel4(float4 v, int h){
    float lo = (h & 1) ? v.y : v.x;
    float hi = (h & 1) ? v.w : v.z;
    return (h & 2) ? hi : lo;
}

// ---------------- W transpose (tiny, once per launch) ----------------
__global__ __launch_bounds__(256) void k_transpose(const float* __restrict__ Wsrc,
        const float* __restrict__ Wres, float* __restrict__ WTs, float* __restrict__ WTr){
    int t = blockIdx.x*256 + threadIdx.x;  // 0..16383
    if (t < 16384){
        int j = t >> 7, k = t & 127;       // coalesced read over k
        WTs[k*128 + j] = Wsrc[t];
        WTr[k*128 + j] = Wres[t];
    }
}

// ---------------- GEMM: xp = feats@Wsrc^T, res(d_out) = feats@Wres^T ----------------
__global__ __launch_bounds__(256) void k_gemm(const float* __restrict__ feats,
        const float* __restrict__ WTs, const float* __restrict__ WTr,
        float* __restrict__ xp, float* __restrict__ res, int n){
    __shared__ float fs[64][128];
    int t = threadIdx.x;
    int n0 = blockIdx.x * 64;
    const float4* f4 = (const float4*)feats;
    #pragma unroll
    for (int i = 0; i < 8; ++i){
        int idx = t + i*256;               // 2048 float4 units
        int row = idx >> 5, c4 = idx & 31;
        float4 v = make_float4(0.f,0.f,0.f,0.f);
        if (n0 + row < n) v = f4[(size_t)(n0+row)*32 + c4];
        fs[row][c4*4+0]=v.x; fs[row][c4*4+1]=v.y; fs[row][c4*4+2]=v.z; fs[row][c4*4+3]=v.w;
    }
    __syncthreads();
    int tn = t >> 5;          // 8 node groups
    int tc = t & 31;          // 32 col groups
    int j0 = tc*4;
    float acc[8][4], acr[8][4];
    #pragma unroll
    for(int i=0;i<8;++i){
        #pragma unroll
        for(int c=0;c<4;++c){ acc[i][c]=0.f; acr[i][c]=0.f; }
    }
    #pragma unroll 4
    for (int k=0;k<128;++k){
        float4 wv = *(const float4*)(WTs + k*128 + j0);
        float4 rv = *(const float4*)(WTr + k*128 + j0);
        #pragma unroll
        for (int i=0;i<8;++i){
            float f = fs[tn*8+i][k];
            acc[i][0]+=f*wv.x; acc[i][1]+=f*wv.y; acc[i][2]+=f*wv.z; acc[i][3]+=f*wv.w;
            acr[i][0]+=f*rv.x; acr[i][1]+=f*rv.y; acr[i][2]+=f*rv.z; acr[i][3]+=f*rv.w;
        }
    }
    #pragma unroll
    for(int i=0;i<8;++i){
        int nn = n0 + tn*8 + i;
        if (nn < n){
            *(float4*)(xp  + (size_t)nn*128 + j0) = make_float4(acc[i][0],acc[i][1],acc[i][2],acc[i][3]);
            *(float4*)(res + (size_t)nn*128 + j0) = make_float4(acr[i][0],acr[i][1],acr[i][2],acr[i][3]);
        }
    }
}

// ---------------- attention scalar per node: a = sum_c xp[n,h,c]*att[h,c] ----------------
__global__ __launch_bounds__(256) void k_attn(const float* __restrict__ xp,
        const float* __restrict__ att_s, const float* __restrict__ att_d,
        float* __restrict__ a_src, float* __restrict__ a_dst, int n){
    int w = threadIdx.x >> 6, lane = threadIdx.x & 63;
    int node = blockIdx.x*4 + w;
    if (node >= n) return;
    float x0 = xp[(size_t)node*128 + lane];
    float x1 = xp[(size_t)node*128 + 64 + lane];
    float s0 = x0 * att_s[lane],    s1 = x1 * att_s[64+lane];
    float d0 = x0 * att_d[lane],    d1 = x1 * att_d[64+lane];
    #pragma unroll
    for (int off=16; off; off>>=1){
        s0 += __shfl_xor(s0, off); s1 += __shfl_xor(s1, off);
        d0 += __shfl_xor(d0, off); d1 += __shfl_xor(d1, off);
    }
    if ((lane & 31) == 0){
        int h = lane >> 5;  // 0 or 1
        a_src[node*4 + h]     = s0;
        a_src[node*4 + 2 + h] = s1;
        a_dst[node*4 + h]     = d0;
        a_dst[node*4 + 2 + h] = d1;
    }
}

// ---------------- CSR build ----------------
__global__ void k_deg(const int* __restrict__ ei, int* __restrict__ deg, int e){
    int i = blockIdx.x*blockDim.x + threadIdx.x;
    if (i < e) atomicAdd(&deg[ei[e + i]], 1);
}

__global__ __launch_bounds__(256) void k_bsum(const int* __restrict__ deg, int* __restrict__ bsum, int n){
    __shared__ int sm[256];
    int i = blockIdx.x*256 + threadIdx.x;
    sm[threadIdx.x] = (i<n)? deg[i] : 0;
    __syncthreads();
    for (int s=128; s; s>>=1){ if ((int)threadIdx.x < s) sm[threadIdx.x]+=sm[threadIdx.x+s]; __syncthreads(); }
    if (!threadIdx.x) bsum[blockIdx.x] = sm[0];
}

__global__ void k_bscan(const int* __restrict__ bsum, int* __restrict__ boff, int nb){
    if (threadIdx.x==0 && blockIdx.x==0){
        int run=0;
        for (int b=0;b<nb;++b){ boff[b]=run; run+=bsum[b]; }
    }
}

__global__ __launch_bounds__(256) void k_scan(const int* __restrict__ deg, const int* __restrict__ boff,
        int* __restrict__ offs, int n){
    __shared__ int sm[256];
    int i = blockIdx.x*256 + threadIdx.x;
    int v = (i<n)? deg[i]:0;
    sm[threadIdx.x]=v;
    __syncthreads();
    for (int s=1;s<256;s<<=1){
        int add = ((int)threadIdx.x>=s)? sm[threadIdx.x-s]:0;
        __syncthreads();
        sm[threadIdx.x]+=add;
        __syncthreads();
    }
    int excl = sm[threadIdx.x]-v;
    if (i<=n) offs[i]=boff[blockIdx.x]+excl;
}

__global__ void k_scatter(const int* __restrict__ ei, const int* __restrict__ offs,
        int* __restrict__ cursor, int* __restrict__ nbr, int e){
    int i = blockIdx.x*blockDim.x + threadIdx.x;
    if (i<e){
        int s = ei[i], d = ei[e+i];
        int pos = atomicAdd(&cursor[d],1);
        nbr[offs[d]+pos] = s;
    }
}

// ---------------- fused softmax + aggregation + residual + BN partials ----------------
// One wave per node. 4 edge-groups x 16 lanes; each lane owns 8 channels (2 float4).
// No max-subtraction: e = lrelu(a_s+a_d) is O(1)-bounded, exp() is safe in fp32 and
// the softmax is shift-invariant, so results match the reference.
__global__ __launch_bounds__(256) void k_aggr(const float* __restrict__ xp,
        const float* __restrict__ a_src, const float* __restrict__ a_dst,
        const int* __restrict__ offs, const int* __restrict__ nbr,
        const float* __restrict__ bias, float* __restrict__ out,
        float* __restrict__ gsum, float* __restrict__ gsq, int n){
    __shared__ float lsum[4][128];
    __shared__ float lsq[4][128];
    int w = threadIdx.x >> 6, lane = threadIdx.x & 63;
    int sub = lane & 15, g = lane >> 4;     // group g handles edge base+g
    int h = sub >> 2;                        // head for this lane's 8 channels
    int node = blockIdx.x*4 + w;
    const float4* a4  = (const float4*)a_src;
    const float4* xp4 = (const float4*)xp;
    float4 o0 = make_float4(0.f,0.f,0.f,0.f);
    float4 o1 = make_float4(0.f,0.f,0.f,0.f);
    if (node < n){
        float4 ad  = *(const float4*)(a_dst + node*4);
        float4 asf = a4[node];
        float adh = sel4(ad, h);
        float wself = __expf(lrelu(sel4(asf, h) + adh));
        int beg = offs[node];
        int deg = offs[node+1] - beg;
        float4 accA = make_float4(0.f,0.f,0.f,0.f);
        float4 accB = make_float4(0.f,0.f,0.f,0.f);
        float ssum = 0.f;
        // self loop (only group 0 contributes; duplicated groups are summed later)
        float4 xsA = xp4[(size_t)node*32 + sub*2];
        float4 xsB = xp4[(size_t)node*32 + sub*2 + 1];
        if (g == 0){
            ssum = wself;
            accA.x = wself*xsA.x; accA.y = wself*xsA.y; accA.z = wself*xsA.z; accA.w = wself*xsA.w;
            accB.x = wself*xsB.x; accB.y = wself*xsB.y; accB.z = wself*xsB.z; accB.w = wself*xsB.w;
        }
        for (int ch0 = 0; ch0 < deg; ch0 += 64){
            int cend = min(64, deg - ch0);
            int sidv = 0;
            if (ch0 + lane < deg) sidv = nbr[beg + ch0 + lane];  // one coalesced load per chunk
            // prologue: load group-edge g of this chunk
            int sidc = __shfl(sidv, g);
            float4 avc = a4[sidc];
            float4 xAc = xp4[(size_t)sidc*32 + sub*2];
            float4 xBc = xp4[(size_t)sidc*32 + sub*2 + 1];
            for (int base = 0; base < cend; base += 4){
                // issue next group's loads (2-deep pipeline)
                int nxt = base + 4 + g;
                int sidn = __shfl(sidv, nxt & 63);
                sidn = (nxt < cend) ? sidn : 0;
                float4 avn = a4[sidn];
                float4 xAn = xp4[(size_t)sidn*32 + sub*2];
                float4 xBn = xp4[(size_t)sidn*32 + sub*2 + 1];
                // compute current
                bool vc = (base + g) < cend;
                float aa = sel4(avc, h) + adh;
                float wgt = vc ? __expf(lrelu(aa)) : 0.f;
                ssum += wgt;
                accA.x += wgt*xAc.x; accA.y += wgt*xAc.y; accA.z += wgt*xAc.z; accA.w += wgt*xAc.w;
                accB.x += wgt*xBc.x; accB.y += wgt*xBc.y; accB.z += wgt*xBc.z; accB.w += wgt*xBc.w;
                sidc = sidn; avc = avn; xAc = xAn; xBc = xBn;
            }
        }
        // cross-group reduce (channels identical across groups)
        #pragma unroll
        for (int off = 16; off <= 32; off <<= 1){
            accA.x += __shfl_xor(accA.x, off); accA.y += __shfl_xor(accA.y, off);
            accA.z += __shfl_xor(accA.z, off); accA.w += __shfl_xor(accA.w, off);
            accB.x += __shfl_xor(accB.x, off); accB.y += __shfl_xor(accB.y, off);
            accB.z += __shfl_xor(accB.z, off); accB.w += __shfl_xor(accB.w, off);
            ssum   += __shfl_xor(ssum, off);
        }
        float inv = 1.f/(ssum + 1e-16f);
        if (g == 0){
            float4 r0 = *(const float4*)(out + (size_t)node*128 + sub*8);
            float4 r1 = *(const float4*)(out + (size_t)node*128 + sub*8 + 4);
            float4 b0 = *(const float4*)(bias + sub*8);
            float4 b1 = *(const float4*)(bias + sub*8 + 4);
            o0.x = accA.x*inv + r0.x + b0.x; o0.y = accA.y*inv + r0.y + b0.y;
            o0.z = accA.z*inv + r0.z + b0.z; o0.w = accA.w*inv + r0.w + b0.w;
            o1.x = accB.x*inv + r1.x + b1.x; o1.y = accB.y*inv + r1.y + b1.y;
            o1.z = accB.z*inv + r1.z + b1.z; o1.w = accB.w*inv + r1.w + b1.w;
            *(float4*)(out + (size_t)node*128 + sub*8)     = o0;
            *(float4*)(out + (size_t)node*128 + sub*8 + 4) = o1;
        }
    }
    if (g == 0){
        *(float4*)&lsum[w][sub*8]   = o0;
        *(float4*)&lsum[w][sub*8+4] = o1;
        float4 q0 = make_float4(o0.x*o0.x, o0.y*o0.y, o0.z*o0.z, o0.w*o0.w);
        float4 q1 = make_float4(o1.x*o1.x, o1.y*o1.y, o1.z*o1.z, o1.w*o1.w);
        *(float4*)&lsq[w][sub*8]    = q0;
        *(float4*)&lsq[w][sub*8+4]  = q1;
    }
    __syncthreads();
    int t = threadIdx.x;
    if (t < 128){
        float s = lsum[0][t]+lsum[1][t]+lsum[2][t]+lsum[3][t];
        atomicAdd(&gsum[t], s);
    } else {
        int c = t-128;
        float s = lsq[0][c]+lsq[1][c]+lsq[2][c]+lsq[3][c];
        atomicAdd(&gsq[c], s);
    }
}

// ---------------- BN finalize + apply ----------------
__global__ void k_bnfin(const float* __restrict__ gsum, const float* __restrict__ gsq,
        const float* __restrict__ gamma, const float* __restrict__ beta,
        float* __restrict__ scale, float* __restrict__ shift, int n){
    int t = threadIdx.x;
    if (t < 128){
        float mu  = gsum[t]/(float)n;
        float var = gsq[t]/(float)n - mu*mu;
        float inv = rsqrtf(var + 1e-5f);
        float sc  = inv*gamma[t];
        scale[t] = sc;
        shift[t] = beta[t] - mu*sc;
    }
}

__global__ __launch_bounds__(256) void k_bnapply(float* __restrict__ out,
        const float* __restrict__ scale, const float* __restrict__ shift, long total4){
    __shared__ float sc[128], sh[128];
    if (threadIdx.x < 128){ sc[threadIdx.x]=scale[threadIdx.x]; sh[threadIdx.x]=shift[threadIdx.x]; }
    __syncthreads();
    long i = (long)blockIdx.x*blockDim.x + threadIdx.x;
    if (i < total4){
        float4* o4 = (float4*)out;
        float4 v = o4[i];
        int c = (int)((i & 31) * 4);
        v.x = v.x*sc[c+0]+sh[c+0];
        v.y = v.y*sc[c+1]+sh[c+1];
        v.z = v.z*sc[c+2]+sh[c+2];
        v.w = v.w*sc[c+3]+sh[c+3];
        o4[i]=v;
    }
}

extern "C" void kernel_launch(void* const* d_in, const int* in_sizes, int n_in,
                              void* d_out, int out_size, void* d_ws, size_t ws_size,
                              hipStream_t stream){
    const float* feats      = (const float*)d_in[0];
    const int* ei           = (const int*)d_in[1];   // harness converts int64 -> int32
    const float* Wsrc       = (const float*)d_in[2];
    const float* att_s      = (const float*)d_in[3];
    const float* att_d      = (const float*)d_in[4];
    const float* Wres       = (const float*)d_in[5];
    const float* bias       = (const float*)d_in[6];
    const float* gamma      = (const float*)d_in[7];
    const float* beta       = (const float*)d_in[8];
    int n = in_sizes[0]/128;
    int e = in_sizes[1]/2;
    float* out = (float*)d_out;

    char* w = (char*)d_ws;
    float* xp    = (float*)w; w += (size_t)n*128*4;
    float* a_src = (float*)w; w += (size_t)n*4*4;
    float* a_dst = (float*)w; w += (size_t)n*4*4;
    int*   deg   = (int*)w;   w += (size_t)n*4;
    int*   cursor= (int*)w;   w += (size_t)n*4;
    int*   offs  = (int*)w;   w += ((size_t)n+8)*4;
    int*   nbr   = (int*)w;   w += (size_t)e*4;
    int nb = (n+255)/256;
    int*   bsum  = (int*)w;   w += ((size_t)nb+8)*4;
    int*   boff  = (int*)w;   w += ((size_t)nb+8)*4;
    float* gsum  = (float*)w; w += 512;
    float* gsq   = (float*)w; w += 512;
    float* scale = (float*)w; w += 512;
    float* shift = (float*)w; w += 512;
    float* WTs   = (float*)w; w += 128*128*4;
    float* WTr   = (float*)w; w += 128*128*4;

    hipMemsetAsync(deg,    0, (size_t)n*4, stream);
    hipMemsetAsync(cursor, 0, (size_t)n*4, stream);
    hipMemsetAsync(gsum,   0, 512, stream);
    hipMemsetAsync(gsq,    0, 512, stream);

    k_transpose<<<dim3(64), 256, 0, stream>>>(Wsrc, Wres, WTs, WTr);
    k_gemm<<<dim3((n+63)/64), 256, 0, stream>>>(feats, WTs, WTr, xp, out, n);
    k_attn<<<dim3((n+3)/4), 256, 0, stream>>>(xp, att_s, att_d, a_src, a_dst, n);
    k_deg<<<dim3((e+255)/256), 256, 0, stream>>>(ei, deg, e);
    k_bsum<<<dim3(nb), 256, 0, stream>>>(deg, bsum, n);
    k_bscan<<<dim3(1), 64, 0, stream>>>(bsum, boff, nb);
    k_scan<<<dim3(nb), 256, 0, stream>>>(deg, boff, offs, n);
    k_scatter<<<dim3((e+255)/256), 256, 0, stream>>>(ei, offs, cursor, nbr, e);
    k_aggr<<<dim3((n+3)/4), 256, 0, stream>>>(xp, a_src, a_dst, offs, nbr, bias, out, gsum, gsq, n);
    k_bnfin<<<dim3(1), 128, 0, stream>>>(gsum, gsq, gamma, beta, scale, shift, n);
    long total4 = (long)n*32;
    k_bnapply<<<dim3((int)((total4+255)/256)), 256, 0, stream>>>(out, scale, shift, total4);
}

// Round 4
// 1161.374 us; speedup vs baseline: 1.0114x; 1.0084x over previous
//
#include <hip/hip_runtime.h>

#define NEGS 0.2f

__device__ __forceinline__ float lrelu(float x){ return x > 0.f ? x : NEGS*x; }
__device__ __forceinline__ float sel4(float4 v, int h){
    float lo = (h & 1) ? v.y : v.x;
    float hi = (h & 1) ? v.w : v.z;
    return (h & 2) ? hi : lo;
}

// ---------------- W transpose (tiny, once per launch) ----------------
__global__ __launch_bounds__(256) void k_transpose(const float* __restrict__ Wsrc,
        const float* __restrict__ Wres, float* __restrict__ WTs, float* __restrict__ WTr){
    int t = blockIdx.x*256 + threadIdx.x;  // 0..16383
    if (t < 16384){
        int j = t >> 7, k = t & 127;       // coalesced read over k
        WTs[k*128 + j] = Wsrc[t];
        WTr[k*128 + j] = Wres[t];
    }
}

// ---------------- GEMM: xp = feats@Wsrc^T, res(d_out) = feats@Wres^T ----------------
__global__ __launch_bounds__(256) void k_gemm(const float* __restrict__ feats,
        const float* __restrict__ WTs, const float* __restrict__ WTr,
        float* __restrict__ xp, float* __restrict__ res, int n){
    __shared__ float fs[64][128];
    int t = threadIdx.x;
    int n0 = blockIdx.x * 64;
    const float4* f4 = (const float4*)feats;
    #pragma unroll
    for (int i = 0; i < 8; ++i){
        int idx = t + i*256;               // 2048 float4 units
        int row = idx >> 5, c4 = idx & 31;
        float4 v = make_float4(0.f,0.f,0.f,0.f);
        if (n0 + row < n) v = f4[(size_t)(n0+row)*32 + c4];
        fs[row][c4*4+0]=v.x; fs[row][c4*4+1]=v.y; fs[row][c4*4+2]=v.z; fs[row][c4*4+3]=v.w;
    }
    __syncthreads();
    int tn = t >> 5;          // 8 node groups
    int tc = t & 31;          // 32 col groups
    int j0 = tc*4;
    float acc[8][4], acr[8][4];
    #pragma unroll
    for(int i=0;i<8;++i){
        #pragma unroll
        for(int c=0;c<4;++c){ acc[i][c]=0.f; acr[i][c]=0.f; }
    }
    #pragma unroll 4
    for (int k=0;k<128;++k){
        float4 wv = *(const float4*)(WTs + k*128 + j0);
        float4 rv = *(const float4*)(WTr + k*128 + j0);
        #pragma unroll
        for (int i=0;i<8;++i){
            float f = fs[tn*8+i][k];
            acc[i][0]+=f*wv.x; acc[i][1]+=f*wv.y; acc[i][2]+=f*wv.z; acc[i][3]+=f*wv.w;
            acr[i][0]+=f*rv.x; acr[i][1]+=f*rv.y; acr[i][2]+=f*rv.z; acr[i][3]+=f*rv.w;
        }
    }
    #pragma unroll
    for(int i=0;i<8;++i){
        int nn = n0 + tn*8 + i;
        if (nn < n){
            *(float4*)(xp  + (size_t)nn*128 + j0) = make_float4(acc[i][0],acc[i][1],acc[i][2],acc[i][3]);
            *(float4*)(res + (size_t)nn*128 + j0) = make_float4(acr[i][0],acr[i][1],acr[i][2],acr[i][3]);
        }
    }
}

// ---------------- attention scalar per node: a = sum_c xp[n,h,c]*att[h,c] ----------------
__global__ __launch_bounds__(256) void k_attn(const float* __restrict__ xp,
        const float* __restrict__ att_s, const float* __restrict__ att_d,
        float* __restrict__ a_src, float* __restrict__ a_dst, int n){
    int w = threadIdx.x >> 6, lane = threadIdx.x & 63;
    int node = blockIdx.x*4 + w;
    if (node >= n) return;
    float x0 = xp[(size_t)node*128 + lane];
    float x1 = xp[(size_t)node*128 + 64 + lane];
    float s0 = x0 * att_s[lane],    s1 = x1 * att_s[64+lane];
    float d0 = x0 * att_d[lane],    d1 = x1 * att_d[64+lane];
    #pragma unroll
    for (int off=16; off; off>>=1){
        s0 += __shfl_xor(s0, off); s1 += __shfl_xor(s1, off);
        d0 += __shfl_xor(d0, off); d1 += __shfl_xor(d1, off);
    }
    if ((lane & 31) == 0){
        int h = lane >> 5;  // 0 or 1
        a_src[node*4 + h]     = s0;
        a_src[node*4 + 2 + h] = s1;
        a_dst[node*4 + h]     = d0;
        a_dst[node*4 + 2 + h] = d1;
    }
}

// ---------------- CSR build ----------------
__global__ void k_deg(const int* __restrict__ ei, int* __restrict__ deg, int e){
    int i = blockIdx.x*blockDim.x + threadIdx.x;
    if (i < e) atomicAdd(&deg[ei[e + i]], 1);
}

__global__ __launch_bounds__(256) void k_bsum(const int* __restrict__ deg, int* __restrict__ bsum, int n){
    __shared__ int sm[256];
    int i = blockIdx.x*256 + threadIdx.x;
    sm[threadIdx.x] = (i<n)? deg[i] : 0;
    __syncthreads();
    for (int s=128; s; s>>=1){ if ((int)threadIdx.x < s) sm[threadIdx.x]+=sm[threadIdx.x+s]; __syncthreads(); }
    if (!threadIdx.x) bsum[blockIdx.x] = sm[0];
}

__global__ void k_bscan(const int* __restrict__ bsum, int* __restrict__ boff, int nb){
    if (threadIdx.x==0 && blockIdx.x==0){
        int run=0;
        for (int b=0;b<nb;++b){ boff[b]=run; run+=bsum[b]; }
    }
}

__global__ __launch_bounds__(256) void k_scan(const int* __restrict__ deg, const int* __restrict__ boff,
        int* __restrict__ offs, int n){
    __shared__ int sm[256];
    int i = blockIdx.x*256 + threadIdx.x;
    int v = (i<n)? deg[i]:0;
    sm[threadIdx.x]=v;
    __syncthreads();
    for (int s=1;s<256;s<<=1){
        int add = ((int)threadIdx.x>=s)? sm[threadIdx.x-s]:0;
        __syncthreads();
        sm[threadIdx.x]+=add;
        __syncthreads();
    }
    int excl = sm[threadIdx.x]-v;
    if (i<=n) offs[i]=boff[blockIdx.x]+excl;
}

__global__ void k_scatter(const int* __restrict__ ei, const int* __restrict__ offs,
        int* __restrict__ cursor, int* __restrict__ nbr, int e){
    int i = blockIdx.x*blockDim.x + threadIdx.x;
    if (i<e){
        int s = ei[i], d = ei[e+i];
        int pos = atomicAdd(&cursor[d],1);
        nbr[offs[d]+pos] = s;
    }
}

// ---------------- fused softmax + aggregation + residual + BN partials ----------------
// One wave per node. Chunk = 16 edges; all 16 rows (8 KB) fetched by 8 INDEPENDENT
// row-pair load instructions (lane = e2(1b) x c32(5b): 32 lanes cover one 512B row).
// Softmax needs no max-subtraction: e = lrelu(a_s+a_d) is O(1)-bounded in fp32.
__global__ __launch_bounds__(256) void k_aggr(const float* __restrict__ xp,
        const float* __restrict__ a_src, const float* __restrict__ a_dst,
        const int* __restrict__ offs, const int* __restrict__ nbr,
        const float* __restrict__ bias, float* __restrict__ out,
        float* __restrict__ gsum, float* __restrict__ gsq, int n){
    __shared__ float lsum[4][128];
    __shared__ float lsq[4][128];
    int w = threadIdx.x >> 6, lane = threadIdx.x & 63;
    int c32 = lane & 31;        // float4 slot within 128-ch row
    int e2  = lane >> 5;        // which edge of each pair
    int h   = c32 >> 3;         // head (C=32 -> 8 float4 per head)
    int node = blockIdx.x*4 + w;
    const float4* a4  = (const float4*)a_src;
    const float4* xp4 = (const float4*)xp;
    float4 o = make_float4(0.f,0.f,0.f,0.f);
    if (node < n){
        float4 ad4 = *(const float4*)(a_dst + node*4);
        float adh = sel4(ad4, h);
        int beg = offs[node];
        int deg = offs[node+1] - beg;
        float4 acc = make_float4(0.f,0.f,0.f,0.f);
        float ssum = 0.f;
        // self loop on half e2==0
        {
            float4 as4 = a4[node];
            float ws = __expf(lrelu(sel4(as4, h) + adh));
            float4 xs = xp4[(size_t)node*32 + c32];
            if (e2 == 0){
                ssum = ws;
                acc.x = ws*xs.x; acc.y = ws*xs.y; acc.z = ws*xs.z; acc.w = ws*xs.w;
            }
        }
        for (int ch0 = 0; ch0 < deg; ch0 += 16){
            int cnt = min(16, deg - ch0);
            // holder lanes (0..15) fetch neighbor ids + their a_src rows
            int sidv = 0;
            if (lane < cnt) sidv = nbr[beg + ch0 + lane];
            float4 av = make_float4(0.f,0.f,0.f,0.f);
            if (lane < cnt) av = a4[sidv];
            // holder lanes compute all-4-head weights for their edge
            float4 w4;
            w4.x = __expf(lrelu(av.x + ad4.x));
            w4.y = __expf(lrelu(av.y + ad4.y));
            w4.z = __expf(lrelu(av.z + ad4.z));
            w4.w = __expf(lrelu(av.w + ad4.w));
            // issue the 8 independent row-pair loads (this lane covers edge p*2+e2)
            float4 xv[8];
            int    ok[8];
            #pragma unroll
            for (int p = 0; p < 8; ++p){
                int j = p*2 + e2;
                int sid = __shfl(sidv, j);
                ok[p] = (j < cnt);
                xv[p] = make_float4(0.f,0.f,0.f,0.f);
                if (ok[p]) xv[p] = xp4[(size_t)sid*32 + c32];
            }
            // distribute weights and accumulate
            #pragma unroll
            for (int p = 0; p < 8; ++p){
                int j = p*2 + e2;
                float4 wv;
                wv.x = __shfl(w4.x, j); wv.y = __shfl(w4.y, j);
                wv.z = __shfl(w4.z, j); wv.w = __shfl(w4.w, j);
                float wgt = ok[p] ? sel4(wv, h) : 0.f;
                ssum += wgt;
                acc.x += wgt*xv[p].x; acc.y += wgt*xv[p].y;
                acc.z += wgt*xv[p].z; acc.w += wgt*xv[p].w;
            }
        }
        // combine the two edge-halves
        acc.x += __shfl_xor(acc.x, 32); acc.y += __shfl_xor(acc.y, 32);
        acc.z += __shfl_xor(acc.z, 32); acc.w += __shfl_xor(acc.w, 32);
        ssum  += __shfl_xor(ssum, 32);
        float inv = 1.f/(ssum + 1e-16f);
        if (e2 == 0){
            float4 r = *(const float4*)(out + (size_t)node*128 + c32*4);
            float4 b = *(const float4*)(bias + c32*4);
            o.x = acc.x*inv + r.x + b.x; o.y = acc.y*inv + r.y + b.y;
            o.z = acc.z*inv + r.z + b.z; o.w = acc.w*inv + r.w + b.w;
            *(float4*)(out + (size_t)node*128 + c32*4) = o;
        }
    }
    if (e2 == 0){
        *(float4*)&lsum[w][c32*4] = o;
        float4 q = make_float4(o.x*o.x, o.y*o.y, o.z*o.z, o.w*o.w);
        *(float4*)&lsq[w][c32*4]  = q;
    }
    __syncthreads();
    int t = threadIdx.x;
    if (t < 128){
        float s = lsum[0][t]+lsum[1][t]+lsum[2][t]+lsum[3][t];
        atomicAdd(&gsum[t], s);
    } else {
        int c = t-128;
        float s = lsq[0][c]+lsq[1][c]+lsq[2][c]+lsq[3][c];
        atomicAdd(&gsq[c], s);
    }
}

// ---------------- BN finalize + apply ----------------
__global__ void k_bnfin(const float* __restrict__ gsum, const float* __restrict__ gsq,
        const float* __restrict__ gamma, const float* __restrict__ beta,
        float* __restrict__ scale, float* __restrict__ shift, int n){
    int t = threadIdx.x;
    if (t < 128){
        float mu  = gsum[t]/(float)n;
        float var = gsq[t]/(float)n - mu*mu;
        float inv = rsqrtf(var + 1e-5f);
        float sc  = inv*gamma[t];
        scale[t] = sc;
        shift[t] = beta[t] - mu*sc;
    }
}

__global__ __launch_bounds__(256) void k_bnapply(float* __restrict__ out,
        const float* __restrict__ scale, const float* __restrict__ shift, long total4){
    __shared__ float sc[128], sh[128];
    if (threadIdx.x < 128){ sc[threadIdx.x]=scale[threadIdx.x]; sh[threadIdx.x]=shift[threadIdx.x]; }
    __syncthreads();
    long i = (long)blockIdx.x*blockDim.x + threadIdx.x;
    if (i < total4){
        float4* o4 = (float4*)out;
        float4 v = o4[i];
        int c = (int)((i & 31) * 4);
        v.x = v.x*sc[c+0]+sh[c+0];
        v.y = v.y*sc[c+1]+sh[c+1];
        v.z = v.z*sc[c+2]+sh[c+2];
        v.w = v.w*sc[c+3]+sh[c+3];
        o4[i]=v;
    }
}

extern "C" void kernel_launch(void* const* d_in, const int* in_sizes, int n_in,
                              void* d_out, int out_size, void* d_ws, size_t ws_size,
                              hipStream_t stream){
    const float* feats      = (const float*)d_in[0];
    const int* ei           = (const int*)d_in[1];   // harness converts int64 -> int32
    const float* Wsrc       = (const float*)d_in[2];
    const float* att_s      = (const float*)d_in[3];
    const float* att_d      = (const float*)d_in[4];
    const float* Wres       = (const float*)d_in[5];
    const float* bias       = (const float*)d_in[6];
    const float* gamma      = (const float*)d_in[7];
    const float* beta       = (const float*)d_in[8];
    int n = in_sizes[0]/128;
    int e = in_sizes[1]/2;
    float* out = (float*)d_out;

    char* w = (char*)d_ws;
    float* xp    = (float*)w; w += (size_t)n*128*4;
    float* a_src = (float*)w; w += (size_t)n*4*4;
    float* a_dst = (float*)w; w += (size_t)n*4*4;
    int*   deg   = (int*)w;   w += (size_t)n*4;
    int*   cursor= (int*)w;   w += (size_t)n*4;
    int*   offs  = (int*)w;   w += ((size_t)n+8)*4;
    int*   nbr   = (int*)w;   w += (size_t)e*4;
    int nb = (n+255)/256;
    int*   bsum  = (int*)w;   w += ((size_t)nb+8)*4;
    int*   boff  = (int*)w;   w += ((size_t)nb+8)*4;
    float* gsum  = (float*)w; w += 512;
    float* gsq   = (float*)w; w += 512;
    float* scale = (float*)w; w += 512;
    float* shift = (float*)w; w += 512;
    float* WTs   = (float*)w; w += 128*128*4;
    float* WTr   = (float*)w; w += 128*128*4;

    hipMemsetAsync(deg,    0, (size_t)n*4, stream);
    hipMemsetAsync(cursor, 0, (size_t)n*4, stream);
    hipMemsetAsync(gsum,   0, 512, stream);
    hipMemsetAsync(gsq,    0, 512, stream);

    k_transpose<<<dim3(64), 256, 0, stream>>>(Wsrc, Wres, WTs, WTr);
    k_gemm<<<dim3((n+63)/64), 256, 0, stream>>>(feats, WTs, WTr, xp, out, n);
    k_attn<<<dim3((n+3)/4), 256, 0, stream>>>(xp, att_s, att_d, a_src, a_dst, n);
    k_deg<<<dim3((e+255)/256), 256, 0, stream>>>(ei, deg, e);
    k_bsum<<<dim3(nb), 256, 0, stream>>>(deg, bsum, n);
    k_bscan<<<dim3(1), 64, 0, stream>>>(bsum, boff, nb);
    k_scan<<<dim3(nb), 256, 0, stream>>>(deg, boff, offs, n);
    k_scatter<<<dim3((e+255)/256), 256, 0, stream>>>(ei, offs, cursor, nbr, e);
    k_aggr<<<dim3((n+3)/4), 256, 0, stream>>>(xp, a_src, a_dst, offs, nbr, bias, out, gsum, gsq, n);
    k_bnfin<<<dim3(1), 128, 0, stream>>>(gsum, gsq, gamma, beta, scale, shift, n);
    long total4 = (long)n*32;
    k_bnapply<<<dim3((int)((total4+255)/256)), 256, 0, stream>>>(out, scale, shift, total4);
}